// Round 3
// baseline (637.792 us; speedup 1.0000x reference)
//
#include <hip/hip_runtime.h>
#include <hip/hip_bf16.h>

#define N_NODES 50000
#define N_EDGES 600000
#define D_IN    128
#define D_HID   1024
#define D_OUT   128

// ---------------------------------------------------------------------------
// Workspace layout (bytes):
//   pairs  : [N_EDGES] int2       @ 0            ( 4,800,000)  {eid, src}
//   off    : [N_NODES+1] int      @  4,800,000   (   200,016)
//   cursor : [N_NODES] int        @  5,000,016   (   200,000)
//   deg    : [N_NODES] int        @  5,200,016   (   200,000)
//   bsum   : [256] int            @  5,400,016   (     1,024)
//   W1T    : [1024*128] bf16      @  5,401,040   (   262,144)   [n][k]
//   W2T    : [128*1024] bf16      @  5,663,184   (   262,144)   [n][k]
// ---------------------------------------------------------------------------
#define WS_PAIRS  0
#define WS_OFF    4800000
#define WS_CURSOR 5000016
#define WS_DEG    5200016
#define WS_BSUM   5400016
#define WS_W1T    5401040
#define WS_W2T    5663184

typedef short bf16x8 __attribute__((ext_vector_type(8)));
typedef float f32x4  __attribute__((ext_vector_type(4)));
typedef int   i32x2  __attribute__((ext_vector_type(2)));

// ---------------------------------------------------------------------------
// CSR step 1: histogram of dst
// ---------------------------------------------------------------------------
__global__ __launch_bounds__(256) void hist_kernel(
    const int* __restrict__ dst, int* __restrict__ deg)
{
    int e = blockIdx.x * blockDim.x + threadIdx.x;
    if (e < N_EDGES) atomicAdd(&deg[dst[e]], 1);
}

// ---------------------------------------------------------------------------
// CSR step 2a: per-block sums of deg (coalesced). 196 blocks x 256.
// ---------------------------------------------------------------------------
__global__ __launch_bounds__(256) void scan1_kernel(
    const int* __restrict__ deg, int* __restrict__ bsum)
{
    __shared__ int red[256];
    int t = threadIdx.x;
    int idx = blockIdx.x * 256 + t;
    red[t] = (idx < N_NODES) ? deg[idx] : 0;
    __syncthreads();
    for (int s = 128; s > 0; s >>= 1) {
        if (t < s) red[t] += red[t + s];
        __syncthreads();
    }
    if (t == 0) bsum[blockIdx.x] = red[0];
}

// ---------------------------------------------------------------------------
// CSR step 2b: exclusive scan of 196 block sums (single small block).
// Also writes off[N_NODES] = total.
// ---------------------------------------------------------------------------
#define SCAN_NB 196
__global__ __launch_bounds__(256) void scan2_kernel(
    int* __restrict__ bsum, int* __restrict__ off)
{
    __shared__ int sh[256];
    int t = threadIdx.x;
    int v = (t < SCAN_NB) ? bsum[t] : 0;
    sh[t] = v;
    __syncthreads();
    for (int ofs = 1; ofs < 256; ofs <<= 1) {
        int u = (t >= ofs) ? sh[t - ofs] : 0;
        __syncthreads();
        sh[t] += u;
        __syncthreads();
    }
    if (t < SCAN_NB) bsum[t] = sh[t] - v;       // exclusive
    if (t == 255) off[N_NODES] = sh[255];       // total == N_EDGES
}

// ---------------------------------------------------------------------------
// CSR step 2c: block-local scan + block offset -> off[], cursor[]
// ---------------------------------------------------------------------------
__global__ __launch_bounds__(256) void scan3_kernel(
    const int* __restrict__ deg, const int* __restrict__ bsum,
    int* __restrict__ off, int* __restrict__ cursor)
{
    __shared__ int sh[256];
    int t = threadIdx.x;
    int idx = blockIdx.x * 256 + t;
    int v = (idx < N_NODES) ? deg[idx] : 0;
    sh[t] = v;
    __syncthreads();
    for (int ofs = 1; ofs < 256; ofs <<= 1) {
        int u = (t >= ofs) ? sh[t - ofs] : 0;
        __syncthreads();
        sh[t] += u;
        __syncthreads();
    }
    if (idx < N_NODES) {
        int ex = bsum[blockIdx.x] + sh[t] - v;
        off[idx] = ex;
        cursor[idx] = ex;
    }
}

// ---------------------------------------------------------------------------
// CSR step 3: drop {eid, src} pairs into dst buckets.
// ---------------------------------------------------------------------------
__global__ __launch_bounds__(256) void fill_kernel(
    const int* __restrict__ dst, const int* __restrict__ src,
    int* __restrict__ cursor, int* __restrict__ pairs)
{
    int e = blockIdx.x * blockDim.x + threadIdx.x;
    if (e < N_EDGES) {
        int s = src[e];                       // coalesced
        int pos = atomicAdd(&cursor[dst[e]], 1);
        i32x2 v; v.x = e; v.y = s;
        *(i32x2*)(pairs + 2 * (size_t)pos) = v;   // 8B scatter
    }
}

// ---------------------------------------------------------------------------
// Merged transpose + fp32->bf16 convert for BOTH weight matrices in one
// launch. Blocks [0,128): W1[128][1024] -> W1T[1024][128].
// Blocks [128,256): W2[1024][128] -> W2T[128][1024].
// ---------------------------------------------------------------------------
__global__ __launch_bounds__(256) void transpose_cvt2_kernel(
    const float* __restrict__ W1, __hip_bfloat16* __restrict__ w1t,
    const float* __restrict__ W2, __hip_bfloat16* __restrict__ w2t)
{
    __shared__ float tile[32][33];
    int b = blockIdx.x;
    const float* in;
    __hip_bfloat16* outp;
    int rows, cols, c0, r0;
    if (b < 128) {
        in = W1; outp = w1t; rows = D_IN; cols = D_HID;
        c0 = (b & 31) * 32; r0 = (b >> 5) * 32;          // grid (32,4)
    } else {
        int bb = b - 128;
        in = W2; outp = w2t; rows = D_HID; cols = D_OUT;
        c0 = (bb & 3) * 32; r0 = (bb >> 2) * 32;         // grid (4,32)
    }
    int tx = threadIdx.x & 31, ty = threadIdx.x >> 5;    // ty 0..7
    #pragma unroll
    for (int i = 0; i < 32; i += 8)
        tile[ty + i][tx] = in[(size_t)(r0 + ty + i) * cols + (c0 + tx)];
    __syncthreads();
    #pragma unroll
    for (int i = 0; i < 32; i += 8)
        outp[(size_t)(c0 + ty + i) * rows + (r0 + tx)] =
            __float2bfloat16(tile[tx][ty + i]);
}

// ---------------------------------------------------------------------------
// FUSED gather + MFMA MLP. 64 nodes/block, 4 waves.
//
// Phase 1 (gather, EDGE-STREAMING): wave wv owns rows r0=16wv..+15 and the
//   contiguous edge range [off[nb+r0], off[nb+r0+16]) (~192 edges). One long
//   loop over edges, 8-edge unroll: 8 wave-uniform {eid,src} pair loads +
//   16 coalesced 512B row loads (float2/lane) all in flight before any
//   consumption (~8KB/wave outstanding, continuously). Accumulate into a
//   register float2; edges of a node are consecutive and wave-exclusive, so
//   on a (wave-uniform, register-compare) node-boundary crossing the acc is
//   flushed as bf16x2 straight into h_s. ~16 flushes per ~192 edges. No
//   shfl chains, no per-node vmcnt drains.
//
// Phase 2 (MLP): unchanged (double-buffered q_s, 1 barrier/64-col chunk).
// ---------------------------------------------------------------------------
#define HS_STRIDE 136   // shorts per h_s row (272 B = 17*16, banks shift 4/row)
#define QS_STRIDE 72    // shorts per q_s row (144 B =  9*16)

__global__ __launch_bounds__(256) void fused_gnn_kernel(
    const float* __restrict__ feat,
    const float* __restrict__ edge_feat,
    const int*   __restrict__ pairs,          // [E] {eid, src}
    const int*   __restrict__ off,
    const __hip_bfloat16* __restrict__ w1t,   // [1024][128]
    const float* __restrict__ b1,             // [1024]
    const __hip_bfloat16* __restrict__ w2t,   // [128][1024]
    const float* __restrict__ b2,             // [128]
    float* __restrict__ out)                  // [N][128]
{
    __shared__ __align__(16) short h_s[64 * HS_STRIDE];      // 17.4 KB
    __shared__ __align__(16) short q_s[2][64 * QS_STRIDE];   // 18.4 KB
    __shared__ int off_s[65];

    const int t    = threadIdx.x;
    const int wv   = t >> 6;
    const int lane = t & 63;
    const int half = lane >> 4;    // quad 0..3 (MFMA layout)
    const int lid  = lane & 15;
    const int nb   = blockIdx.x * 64;

    const short* w1s = (const short*)w1t;
    const short* w2s = (const short*)w2t;

    // ---- stage off[] boundaries for the block's 64 rows ----
    if (t < 65) {
        int oidx = nb + t;
        off_s[t] = off[oidx > N_NODES ? N_NODES : oidx];
    }
    __syncthreads();

    // ---- phase 1: edge-streaming gather straight into h_s ----
    {
        const int r0  = wv * 16;
        int cur = r0;                  // local row currently accumulating
        int nxt = off_s[r0 + 1];       // global edge idx where row cur ends
        const int i0  = off_s[r0];
        const int end = off_s[r0 + 16];
        float2 acc = make_float2(0.f, 0.f);

        // flush acc into h_s[cur], advance to next row
        #define FLUSH_ROW() do {                                            \
            __hip_bfloat162 hv_;                                            \
            hv_.x = __float2bfloat16(acc.x);                                \
            hv_.y = __float2bfloat16(acc.y);                                \
            *(__hip_bfloat162*)&h_s[cur * HS_STRIDE + lane * 2] = hv_;      \
            acc.x = 0.f; acc.y = 0.f;                                       \
            ++cur; nxt = off_s[cur + 1];                                    \
        } while (0)

        #define EDGE_ACC(K, EV, GV) do {                                    \
            while (i + (K) >= nxt) FLUSH_ROW();                             \
            acc.x += EV.x + GV.x;                                           \
            acc.y += EV.y + GV.y;                                           \
        } while (0)

        int i = i0;
        for (; i + 8 <= end; i += 8) {
            i32x2 p0 = *(const i32x2*)(pairs + 2 * (size_t)(i + 0));
            i32x2 p1 = *(const i32x2*)(pairs + 2 * (size_t)(i + 1));
            i32x2 p2 = *(const i32x2*)(pairs + 2 * (size_t)(i + 2));
            i32x2 p3 = *(const i32x2*)(pairs + 2 * (size_t)(i + 3));
            i32x2 p4 = *(const i32x2*)(pairs + 2 * (size_t)(i + 4));
            i32x2 p5 = *(const i32x2*)(pairs + 2 * (size_t)(i + 5));
            i32x2 p6 = *(const i32x2*)(pairs + 2 * (size_t)(i + 6));
            i32x2 p7 = *(const i32x2*)(pairs + 2 * (size_t)(i + 7));
            float2 e0 = ((const float2*)(edge_feat + (size_t)p0.x * D_IN))[lane];
            float2 g0 = ((const float2*)(feat      + (size_t)p0.y * D_IN))[lane];
            float2 e1 = ((const float2*)(edge_feat + (size_t)p1.x * D_IN))[lane];
            float2 g1 = ((const float2*)(feat      + (size_t)p1.y * D_IN))[lane];
            float2 e2 = ((const float2*)(edge_feat + (size_t)p2.x * D_IN))[lane];
            float2 g2 = ((const float2*)(feat      + (size_t)p2.y * D_IN))[lane];
            float2 e3 = ((const float2*)(edge_feat + (size_t)p3.x * D_IN))[lane];
            float2 g3 = ((const float2*)(feat      + (size_t)p3.y * D_IN))[lane];
            float2 e4 = ((const float2*)(edge_feat + (size_t)p4.x * D_IN))[lane];
            float2 g4 = ((const float2*)(feat      + (size_t)p4.y * D_IN))[lane];
            float2 e5 = ((const float2*)(edge_feat + (size_t)p5.x * D_IN))[lane];
            float2 g5 = ((const float2*)(feat      + (size_t)p5.y * D_IN))[lane];
            float2 e6 = ((const float2*)(edge_feat + (size_t)p6.x * D_IN))[lane];
            float2 g6 = ((const float2*)(feat      + (size_t)p6.y * D_IN))[lane];
            float2 e7 = ((const float2*)(edge_feat + (size_t)p7.x * D_IN))[lane];
            float2 g7 = ((const float2*)(feat      + (size_t)p7.y * D_IN))[lane];
            EDGE_ACC(0, e0, g0);
            EDGE_ACC(1, e1, g1);
            EDGE_ACC(2, e2, g2);
            EDGE_ACC(3, e3, g3);
            EDGE_ACC(4, e4, g4);
            EDGE_ACC(5, e5, g5);
            EDGE_ACC(6, e6, g6);
            EDGE_ACC(7, e7, g7);
        }
        for (; i < end; ++i) {
            i32x2 p = *(const i32x2*)(pairs + 2 * (size_t)i);
            float2 e = ((const float2*)(edge_feat + (size_t)p.x * D_IN))[lane];
            float2 g = ((const float2*)(feat      + (size_t)p.y * D_IN))[lane];
            EDGE_ACC(0, e, g);
        }
        // flush last accumulating row + zero-fill any trailing empty rows
        while (cur < r0 + 16) {
            __hip_bfloat162 hv_;
            hv_.x = __float2bfloat16(acc.x);
            hv_.y = __float2bfloat16(acc.y);
            *(__hip_bfloat162*)&h_s[cur * HS_STRIDE + lane * 2] = hv_;
            acc.x = 0.f; acc.y = 0.f;
            ++cur;
        }
        #undef EDGE_ACC
        #undef FLUSH_ROW
    }
    __syncthreads();

    // ---- A fragments for layer 1 (held in registers for all chunks) ----
    bf16x8 afrag[4][4];
    #pragma unroll
    for (int mt = 0; mt < 4; ++mt)
        #pragma unroll
        for (int ks = 0; ks < 4; ++ks)
            afrag[mt][ks] = *(const bf16x8*)&h_s[(mt * 16 + lid) * HS_STRIDE + ks * 32 + half * 8];

    f32x4 acc[4][2];
    #pragma unroll
    for (int mt = 0; mt < 4; ++mt) {
        acc[mt][0] = f32x4{0.f, 0.f, 0.f, 0.f};
        acc[mt][1] = f32x4{0.f, 0.f, 0.f, 0.f};
    }

    const int ncol1 = wv * 16 + lid;   // within-chunk hidden column for layer-1 B

    int pb = 0;
    for (int jb = 0; jb < D_HID; jb += 64, pb ^= 1) {
        // ---- layer 1 ----
        float bias = b1[jb + ncol1];
        bf16x8 bfrag[4];
        #pragma unroll
        for (int ks = 0; ks < 4; ++ks)
            bfrag[ks] = *(const bf16x8*)&w1s[(size_t)(jb + ncol1) * 128 + ks * 32 + half * 8];

        f32x4 c1[4];
        #pragma unroll
        for (int mt = 0; mt < 4; ++mt) {
            f32x4 c = f32x4{bias, bias, bias, bias};
            #pragma unroll
            for (int ks = 0; ks < 4; ++ks)
                c = __builtin_amdgcn_mfma_f32_16x16x32_bf16(afrag[mt][ks], bfrag[ks], c, 0, 0, 0);
            c1[mt] = c;
        }

        // write this chunk into q_s[pb]; previous chunk's reads of q_s[pb^1]
        // are separated from the NEXT write to pb^1 by this barrier.
        #pragma unroll
        for (int mt = 0; mt < 4; ++mt) {
            #pragma unroll
            for (int r = 0; r < 4; ++r) {
                float v = fmaxf(c1[mt][r], 0.f);
                __hip_bfloat16 bv = __float2bfloat16(v);
                q_s[pb][(mt * 16 + half * 4 + r) * QS_STRIDE + wv * 16 + lid] = *(short*)&bv;
            }
        }
        __syncthreads();

        // ---- layer 2 ----
        bf16x8 a2f[4][2];
        #pragma unroll
        for (int mt = 0; mt < 4; ++mt)
            #pragma unroll
            for (int ks = 0; ks < 2; ++ks)
                a2f[mt][ks] = *(const bf16x8*)&q_s[pb][(mt * 16 + lid) * QS_STRIDE + ks * 32 + half * 8];

        #pragma unroll
        for (int nt = 0; nt < 2; ++nt) {
            #pragma unroll
            for (int ks = 0; ks < 2; ++ks) {
                bf16x8 b2f = *(const bf16x8*)&w2s[(size_t)(wv * 32 + nt * 16 + lid) * 1024 + jb + ks * 32 + half * 8];
                #pragma unroll
                for (int mt = 0; mt < 4; ++mt)
                    acc[mt][nt] = __builtin_amdgcn_mfma_f32_16x16x32_bf16(a2f[mt][ks], b2f, acc[mt][nt], 0, 0, 0);
            }
        }
    }

    // ---- epilogue ----
    #pragma unroll
    for (int nt = 0; nt < 2; ++nt) {
        int col = wv * 32 + nt * 16 + lid;
        float bv = b2[col];
        #pragma unroll
        for (int mt = 0; mt < 4; ++mt) {
            #pragma unroll
            for (int r = 0; r < 4; ++r) {
                int row = nb + mt * 16 + half * 4 + r;
                if (row < N_NODES)
                    out[(size_t)row * D_OUT + col] = acc[mt][nt][r] + bv;
            }
        }
    }
}

// ---------------------------------------------------------------------------
extern "C" void kernel_launch(void* const* d_in, const int* in_sizes, int n_in,
                              void* d_out, int out_size, void* d_ws, size_t ws_size,
                              hipStream_t stream) {
    const float* feat      = (const float*)d_in[0];
    const float* edge_feat = (const float*)d_in[1];
    const int*   src       = (const int*)d_in[2];
    const int*   dst       = (const int*)d_in[3];
    const float* W1        = (const float*)d_in[4];
    const float* b1        = (const float*)d_in[5];
    const float* W2        = (const float*)d_in[6];
    const float* b2        = (const float*)d_in[7];
    float* out = (float*)d_out;

    char* ws = (char*)d_ws;
    int*   pairs  = (int*)(ws + WS_PAIRS);
    int*   off    = (int*)(ws + WS_OFF);
    int*   cursor = (int*)(ws + WS_CURSOR);
    int*   deg    = (int*)(ws + WS_DEG);
    int*   bsum   = (int*)(ws + WS_BSUM);
    __hip_bfloat16* w1t = (__hip_bfloat16*)(ws + WS_W1T);
    __hip_bfloat16* w2t = (__hip_bfloat16*)(ws + WS_W2T);

    hipMemsetAsync(deg, 0, (size_t)N_NODES * sizeof(int), stream);

    // CSR build
    hist_kernel<<<(N_EDGES + 255) / 256, 256, 0, stream>>>(dst, deg);
    scan1_kernel<<<SCAN_NB, 256, 0, stream>>>(deg, bsum);
    scan2_kernel<<<1, 256, 0, stream>>>(bsum, off);
    scan3_kernel<<<SCAN_NB, 256, 0, stream>>>(deg, bsum, off, cursor);
    fill_kernel<<<(N_EDGES + 255) / 256, 256, 0, stream>>>(dst, src, cursor, pairs);

    // both weight transposes in one launch
    transpose_cvt2_kernel<<<256, 256, 0, stream>>>(W1, w1t, W2, w2t);

    // fused gather + MFMA MLP
    fused_gnn_kernel<<<(N_NODES + 63) / 64, 256, 0, stream>>>(
        feat, edge_feat, pairs, off, w1t, b1, w2t, b2, out);
}

// Round 4
// 611.603 us; speedup vs baseline: 1.0428x; 1.0428x over previous
//
#include <hip/hip_runtime.h>
#include <hip/hip_bf16.h>

#define N_NODES 50000
#define N_EDGES 600000
#define D_IN    128
#define D_HID   1024
#define D_OUT   128

// ---------------------------------------------------------------------------
// Workspace layout (bytes):
//   hbf    : [N_NODES*128] bf16   @ 0            (12,800,000)
//   pairs  : [N_EDGES] int2       @ 12,800,000   ( 4,800,000)  {eid, src}
//   off    : [N_NODES+1] int      @ 17,600,000   (   200,016)
//   cursor : [N_NODES] int        @ 17,800,016   (   200,000)
//   deg    : [N_NODES] int        @ 18,000,016   (   200,000)
//   bsum   : [256] int            @ 18,200,016   (     1,024)
//   W1T    : [1024*128] bf16      @ 18,201,040   (   262,144)   [n][k]
//   W2T    : [128*1024] bf16      @ 18,463,184   (   262,144)   [n][k]
// ---------------------------------------------------------------------------
#define WS_H      0
#define WS_PAIRS  12800000
#define WS_OFF    17600000
#define WS_CURSOR 17800016
#define WS_DEG    18000016
#define WS_BSUM   18200016
#define WS_W1T    18201040
#define WS_W2T    18463184

typedef short bf16x8 __attribute__((ext_vector_type(8)));
typedef float f32x4  __attribute__((ext_vector_type(4)));
typedef int   i32x2  __attribute__((ext_vector_type(2)));

// ---------------------------------------------------------------------------
// CSR step 1: histogram of dst
// ---------------------------------------------------------------------------
__global__ __launch_bounds__(256) void hist_kernel(
    const int* __restrict__ dst, int* __restrict__ deg)
{
    int e = blockIdx.x * blockDim.x + threadIdx.x;
    if (e < N_EDGES) atomicAdd(&deg[dst[e]], 1);
}

// ---------------------------------------------------------------------------
// CSR step 2a: per-block sums of deg (coalesced). 196 blocks x 256.
// ---------------------------------------------------------------------------
__global__ __launch_bounds__(256) void scan1_kernel(
    const int* __restrict__ deg, int* __restrict__ bsum)
{
    __shared__ int red[256];
    int t = threadIdx.x;
    int idx = blockIdx.x * 256 + t;
    red[t] = (idx < N_NODES) ? deg[idx] : 0;
    __syncthreads();
    for (int s = 128; s > 0; s >>= 1) {
        if (t < s) red[t] += red[t + s];
        __syncthreads();
    }
    if (t == 0) bsum[blockIdx.x] = red[0];
}

// ---------------------------------------------------------------------------
// CSR step 2b: exclusive scan of 196 block sums (single small block).
// Also writes off[N_NODES] = total.
// ---------------------------------------------------------------------------
#define SCAN_NB 196
__global__ __launch_bounds__(256) void scan2_kernel(
    int* __restrict__ bsum, int* __restrict__ off)
{
    __shared__ int sh[256];
    int t = threadIdx.x;
    int v = (t < SCAN_NB) ? bsum[t] : 0;
    sh[t] = v;
    __syncthreads();
    for (int ofs = 1; ofs < 256; ofs <<= 1) {
        int u = (t >= ofs) ? sh[t - ofs] : 0;
        __syncthreads();
        sh[t] += u;
        __syncthreads();
    }
    if (t < SCAN_NB) bsum[t] = sh[t] - v;       // exclusive
    if (t == 255) off[N_NODES] = sh[255];       // total == N_EDGES
}

// ---------------------------------------------------------------------------
// CSR step 2c: block-local scan + block offset -> off[], cursor[]
// ---------------------------------------------------------------------------
__global__ __launch_bounds__(256) void scan3_kernel(
    const int* __restrict__ deg, const int* __restrict__ bsum,
    int* __restrict__ off, int* __restrict__ cursor)
{
    __shared__ int sh[256];
    int t = threadIdx.x;
    int idx = blockIdx.x * 256 + t;
    int v = (idx < N_NODES) ? deg[idx] : 0;
    sh[t] = v;
    __syncthreads();
    for (int ofs = 1; ofs < 256; ofs <<= 1) {
        int u = (t >= ofs) ? sh[t - ofs] : 0;
        __syncthreads();
        sh[t] += u;
        __syncthreads();
    }
    if (idx < N_NODES) {
        int ex = bsum[blockIdx.x] + sh[t] - v;
        off[idx] = ex;
        cursor[idx] = ex;
    }
}

// ---------------------------------------------------------------------------
// CSR step 3: drop {eid, src} pairs into dst buckets.
// ---------------------------------------------------------------------------
__global__ __launch_bounds__(256) void fill_kernel(
    const int* __restrict__ dst, const int* __restrict__ src,
    int* __restrict__ cursor, int* __restrict__ pairs)
{
    int e = blockIdx.x * blockDim.x + threadIdx.x;
    if (e < N_EDGES) {
        int s = src[e];                       // coalesced
        int pos = atomicAdd(&cursor[dst[e]], 1);
        i32x2 v; v.x = e; v.y = s;
        *(i32x2*)(pairs + 2 * (size_t)pos) = v;   // 8B scatter
    }
}

// ---------------------------------------------------------------------------
// Merged transpose + fp32->bf16 convert for BOTH weight matrices in one
// launch. Blocks [0,128): W1[128][1024] -> W1T[1024][128].
// Blocks [128,256): W2[1024][128] -> W2T[128][1024].
// ---------------------------------------------------------------------------
__global__ __launch_bounds__(256) void transpose_cvt2_kernel(
    const float* __restrict__ W1, __hip_bfloat16* __restrict__ w1t,
    const float* __restrict__ W2, __hip_bfloat16* __restrict__ w2t)
{
    __shared__ float tile[32][33];
    int b = blockIdx.x;
    const float* in;
    __hip_bfloat16* outp;
    int rows, cols, c0, r0;
    if (b < 128) {
        in = W1; outp = w1t; rows = D_IN; cols = D_HID;
        c0 = (b & 31) * 32; r0 = (b >> 5) * 32;          // grid (32,4)
    } else {
        int bb = b - 128;
        in = W2; outp = w2t; rows = D_HID; cols = D_OUT;
        c0 = (bb & 3) * 32; r0 = (bb >> 2) * 32;         // grid (4,32)
    }
    int tx = threadIdx.x & 31, ty = threadIdx.x >> 5;    // ty 0..7
    #pragma unroll
    for (int i = 0; i < 32; i += 8)
        tile[ty + i][tx] = in[(size_t)(r0 + ty + i) * cols + (c0 + tx)];
    __syncthreads();
    #pragma unroll
    for (int i = 0; i < 32; i += 8)
        outp[(size_t)(c0 + ty + i) * rows + (r0 + tx)] =
            __float2bfloat16(tile[tx][ty + i]);
}

// ---------------------------------------------------------------------------
// STANDALONE gather: one wave per node, 12.5k blocks -> ~32 resident
// waves/CU (vs ~6 in the fused version; the gather is concurrency-bound, so
// occupancy IS the throughput). Wave-uniform {eid,src} pair loads (scalar),
// full-wave float2/lane row loads (512B coalesced per edge), 8-edge unroll
// into 4 independent accumulators. Low register pressure, no shfl, no LDS.
// Output bf16 row straight to hbf.
// ---------------------------------------------------------------------------
__global__ __launch_bounds__(256) void gather_kernel(
    const float* __restrict__ feat,
    const float* __restrict__ edge_feat,
    const int*   __restrict__ pairs,          // [E] {eid, src}
    const int*   __restrict__ off,
    __hip_bfloat16* __restrict__ hbf)
{
    const int wv   = threadIdx.x >> 6;
    const int lane = threadIdx.x & 63;
    const int n = blockIdx.x * 4 + wv;
    if (n >= N_NODES) return;

    int i   = __builtin_amdgcn_readfirstlane(off[n]);
    int end = __builtin_amdgcn_readfirstlane(off[n + 1]);

    float2 a0 = make_float2(0.f, 0.f), a1 = a0, a2 = a0, a3 = a0;

    for (; i + 8 <= end; i += 8) {
        i32x2 p0 = *(const i32x2*)(pairs + 2 * (size_t)(i + 0));
        i32x2 p1 = *(const i32x2*)(pairs + 2 * (size_t)(i + 1));
        i32x2 p2 = *(const i32x2*)(pairs + 2 * (size_t)(i + 2));
        i32x2 p3 = *(const i32x2*)(pairs + 2 * (size_t)(i + 3));
        i32x2 p4 = *(const i32x2*)(pairs + 2 * (size_t)(i + 4));
        i32x2 p5 = *(const i32x2*)(pairs + 2 * (size_t)(i + 5));
        i32x2 p6 = *(const i32x2*)(pairs + 2 * (size_t)(i + 6));
        i32x2 p7 = *(const i32x2*)(pairs + 2 * (size_t)(i + 7));
        float2 e0 = ((const float2*)(edge_feat + (size_t)p0.x * D_IN))[lane];
        float2 g0 = ((const float2*)(feat      + (size_t)p0.y * D_IN))[lane];
        float2 e1 = ((const float2*)(edge_feat + (size_t)p1.x * D_IN))[lane];
        float2 g1 = ((const float2*)(feat      + (size_t)p1.y * D_IN))[lane];
        float2 e2 = ((const float2*)(edge_feat + (size_t)p2.x * D_IN))[lane];
        float2 g2 = ((const float2*)(feat      + (size_t)p2.y * D_IN))[lane];
        float2 e3 = ((const float2*)(edge_feat + (size_t)p3.x * D_IN))[lane];
        float2 g3 = ((const float2*)(feat      + (size_t)p3.y * D_IN))[lane];
        float2 e4 = ((const float2*)(edge_feat + (size_t)p4.x * D_IN))[lane];
        float2 g4 = ((const float2*)(feat      + (size_t)p4.y * D_IN))[lane];
        float2 e5 = ((const float2*)(edge_feat + (size_t)p5.x * D_IN))[lane];
        float2 g5 = ((const float2*)(feat      + (size_t)p5.y * D_IN))[lane];
        float2 e6 = ((const float2*)(edge_feat + (size_t)p6.x * D_IN))[lane];
        float2 g6 = ((const float2*)(feat      + (size_t)p6.y * D_IN))[lane];
        float2 e7 = ((const float2*)(edge_feat + (size_t)p7.x * D_IN))[lane];
        float2 g7 = ((const float2*)(feat      + (size_t)p7.y * D_IN))[lane];
        a0.x += e0.x + g0.x;  a0.y += e0.y + g0.y;
        a1.x += e1.x + g1.x;  a1.y += e1.y + g1.y;
        a2.x += e2.x + g2.x;  a2.y += e2.y + g2.y;
        a3.x += e3.x + g3.x;  a3.y += e3.y + g3.y;
        a0.x += e4.x + g4.x;  a0.y += e4.y + g4.y;
        a1.x += e5.x + g5.x;  a1.y += e5.y + g5.y;
        a2.x += e6.x + g6.x;  a2.y += e6.y + g6.y;
        a3.x += e7.x + g7.x;  a3.y += e7.y + g7.y;
    }
    for (; i + 2 <= end; i += 2) {
        i32x2 p0 = *(const i32x2*)(pairs + 2 * (size_t)(i + 0));
        i32x2 p1 = *(const i32x2*)(pairs + 2 * (size_t)(i + 1));
        float2 e0 = ((const float2*)(edge_feat + (size_t)p0.x * D_IN))[lane];
        float2 g0 = ((const float2*)(feat      + (size_t)p0.y * D_IN))[lane];
        float2 e1 = ((const float2*)(edge_feat + (size_t)p1.x * D_IN))[lane];
        float2 g1 = ((const float2*)(feat      + (size_t)p1.y * D_IN))[lane];
        a0.x += e0.x + g0.x;  a0.y += e0.y + g0.y;
        a1.x += e1.x + g1.x;  a1.y += e1.y + g1.y;
    }
    if (i < end) {
        i32x2 p = *(const i32x2*)(pairs + 2 * (size_t)i);
        float2 e = ((const float2*)(edge_feat + (size_t)p.x * D_IN))[lane];
        float2 g = ((const float2*)(feat      + (size_t)p.y * D_IN))[lane];
        a0.x += e.x + g.x;  a0.y += e.y + g.y;
    }
    float sx = (a0.x + a1.x) + (a2.x + a3.x);
    float sy = (a0.y + a1.y) + (a2.y + a3.y);
    __hip_bfloat162 hv;
    hv.x = __float2bfloat16(sx);
    hv.y = __float2bfloat16(sy);
    ((__hip_bfloat162*)(hbf + (size_t)n * D_IN))[lane] = hv;
}

// ---------------------------------------------------------------------------
// MFMA MLP. 64 nodes/block, 4 waves.
// Layer1: wave w computes hid[:, jb + w*16 .. +16) -- A (h tile) in regs,
//         B streamed from W1T[n][k] (contiguous 16B frags).
// Hidden chunk relu'd -> bf16 -> q_s[parity] (A-operand layout); q_s is
// double-buffered -> ONE __syncthreads() per 64-col chunk.
// Layer2: wave w computes out[:, w*32 .. +32), K = chunk, B from W2T[n][k].
// ---------------------------------------------------------------------------
#define HS_STRIDE 136   // shorts per h_s row (272 B = 17*16, banks shift 4/row)
#define QS_STRIDE 72    // shorts per q_s row (144 B =  9*16)

__global__ __launch_bounds__(256) void mlp_mfma_kernel(
    const __hip_bfloat16* __restrict__ hbf,   // [N][128]
    const __hip_bfloat16* __restrict__ w1t,   // [1024][128]
    const float* __restrict__ b1,             // [1024]
    const __hip_bfloat16* __restrict__ w2t,   // [128][1024]
    const float* __restrict__ b2,             // [128]
    float* __restrict__ out)                  // [N][128]
{
    __shared__ __align__(16) short h_s[64 * HS_STRIDE];      // 17.4 KB
    __shared__ __align__(16) short q_s[2][64 * QS_STRIDE];   // 18.4 KB

    const int t    = threadIdx.x;
    const int wv   = t >> 6;
    const int lane = t & 63;
    const int half = lane >> 4;    // quad 0..3
    const int lid  = lane & 15;
    const int nb   = blockIdx.x * 64;

    const short* hs  = (const short*)hbf;
    const short* w1s = (const short*)w1t;
    const short* w2s = (const short*)w2t;

    // ---- stage h tile (64 rows x 256 B) ----
    for (int u = t; u < 64 * 16; u += 256) {
        int r = u >> 4, c = u & 15;
        int row = nb + r;
        uint4 v = make_uint4(0u, 0u, 0u, 0u);
        if (row < N_NODES) v = ((const uint4*)(hs + (size_t)row * 128))[c];
        *(uint4*)&h_s[r * HS_STRIDE + c * 8] = v;
    }
    __syncthreads();

    // ---- A fragments for layer 1 (held in registers for all chunks) ----
    bf16x8 afrag[4][4];
    #pragma unroll
    for (int mt = 0; mt < 4; ++mt)
        #pragma unroll
        for (int ks = 0; ks < 4; ++ks)
            afrag[mt][ks] = *(const bf16x8*)&h_s[(mt * 16 + lid) * HS_STRIDE + ks * 32 + half * 8];

    f32x4 acc[4][2];
    #pragma unroll
    for (int mt = 0; mt < 4; ++mt) {
        acc[mt][0] = f32x4{0.f, 0.f, 0.f, 0.f};
        acc[mt][1] = f32x4{0.f, 0.f, 0.f, 0.f};
    }

    const int ncol1 = wv * 16 + lid;   // within-chunk hidden column for layer-1 B

    int pb = 0;
    for (int jb = 0; jb < D_HID; jb += 64, pb ^= 1) {
        // ---- layer 1 ----
        float bias = b1[jb + ncol1];
        bf16x8 bfrag[4];
        #pragma unroll
        for (int ks = 0; ks < 4; ++ks)
            bfrag[ks] = *(const bf16x8*)&w1s[(size_t)(jb + ncol1) * 128 + ks * 32 + half * 8];

        f32x4 c1[4];
        #pragma unroll
        for (int mt = 0; mt < 4; ++mt) {
            f32x4 c = f32x4{bias, bias, bias, bias};
            #pragma unroll
            for (int ks = 0; ks < 4; ++ks)
                c = __builtin_amdgcn_mfma_f32_16x16x32_bf16(afrag[mt][ks], bfrag[ks], c, 0, 0, 0);
            c1[mt] = c;
        }

        // write this chunk into q_s[pb]; previous chunk's reads of q_s[pb^1]
        // are separated from the NEXT write to pb^1 by this barrier.
        #pragma unroll
        for (int mt = 0; mt < 4; ++mt) {
            #pragma unroll
            for (int r = 0; r < 4; ++r) {
                float v = fmaxf(c1[mt][r], 0.f);
                __hip_bfloat16 bv = __float2bfloat16(v);
                q_s[pb][(mt * 16 + half * 4 + r) * QS_STRIDE + wv * 16 + lid] = *(short*)&bv;
            }
        }
        __syncthreads();

        // ---- layer 2 ----
        bf16x8 a2f[4][2];
        #pragma unroll
        for (int mt = 0; mt < 4; ++mt)
            #pragma unroll
            for (int ks = 0; ks < 2; ++ks)
                a2f[mt][ks] = *(const bf16x8*)&q_s[pb][(mt * 16 + lid) * QS_STRIDE + ks * 32 + half * 8];

        #pragma unroll
        for (int nt = 0; nt < 2; ++nt) {
            #pragma unroll
            for (int ks = 0; ks < 2; ++ks) {
                bf16x8 b2f = *(const bf16x8*)&w2s[(size_t)(wv * 32 + nt * 16 + lid) * 1024 + jb + ks * 32 + half * 8];
                #pragma unroll
                for (int mt = 0; mt < 4; ++mt)
                    acc[mt][nt] = __builtin_amdgcn_mfma_f32_16x16x32_bf16(a2f[mt][ks], b2f, acc[mt][nt], 0, 0, 0);
            }
        }
    }

    // ---- epilogue ----
    #pragma unroll
    for (int nt = 0; nt < 2; ++nt) {
        int col = wv * 32 + nt * 16 + lid;
        float bv = b2[col];
        #pragma unroll
        for (int mt = 0; mt < 4; ++mt) {
            #pragma unroll
            for (int r = 0; r < 4; ++r) {
                int row = nb + mt * 16 + half * 4 + r;
                if (row < N_NODES)
                    out[(size_t)row * D_OUT + col] = acc[mt][nt][r] + bv;
            }
        }
    }
}

// ---------------------------------------------------------------------------
extern "C" void kernel_launch(void* const* d_in, const int* in_sizes, int n_in,
                              void* d_out, int out_size, void* d_ws, size_t ws_size,
                              hipStream_t stream) {
    const float* feat      = (const float*)d_in[0];
    const float* edge_feat = (const float*)d_in[1];
    const int*   src       = (const int*)d_in[2];
    const int*   dst       = (const int*)d_in[3];
    const float* W1        = (const float*)d_in[4];
    const float* b1        = (const float*)d_in[5];
    const float* W2        = (const float*)d_in[6];
    const float* b2        = (const float*)d_in[7];
    float* out = (float*)d_out;

    char* ws = (char*)d_ws;
    __hip_bfloat16* hbf = (__hip_bfloat16*)(ws + WS_H);
    int*   pairs  = (int*)(ws + WS_PAIRS);
    int*   off    = (int*)(ws + WS_OFF);
    int*   cursor = (int*)(ws + WS_CURSOR);
    int*   deg    = (int*)(ws + WS_DEG);
    int*   bsum   = (int*)(ws + WS_BSUM);
    __hip_bfloat16* w1t = (__hip_bfloat16*)(ws + WS_W1T);
    __hip_bfloat16* w2t = (__hip_bfloat16*)(ws + WS_W2T);

    hipMemsetAsync(deg, 0, (size_t)N_NODES * sizeof(int), stream);

    // CSR build
    hist_kernel<<<(N_EDGES + 255) / 256, 256, 0, stream>>>(dst, deg);
    scan1_kernel<<<SCAN_NB, 256, 0, stream>>>(deg, bsum);
    scan2_kernel<<<1, 256, 0, stream>>>(bsum, off);
    scan3_kernel<<<SCAN_NB, 256, 0, stream>>>(deg, bsum, off, cursor);
    fill_kernel<<<(N_EDGES + 255) / 256, 256, 0, stream>>>(dst, src, cursor, pairs);

    // both weight transposes in one launch
    transpose_cvt2_kernel<<<256, 256, 0, stream>>>(W1, w1t, W2, w2t);

    // standalone gather at full occupancy (one wave per node)
    gather_kernel<<<(N_NODES + 3) / 4, 256, 0, stream>>>(
        feat, edge_feat, pairs, off, hbf);

    // MFMA MLP
    mlp_mfma_kernel<<<(N_NODES + 63) / 64, 256, 0, stream>>>(
        hbf, w1t, b1, w2t, b2, out);
}

// Round 5
// 605.277 us; speedup vs baseline: 1.0537x; 1.0105x over previous
//
#include <hip/hip_runtime.h>
#include <hip/hip_bf16.h>

#define N_NODES 50000
#define N_EDGES 600000
#define D_IN    128
#define D_HID   1024
#define D_OUT   128

// ---------------------------------------------------------------------------
// Workspace layout (bytes):
//   hbf    : [N_NODES*128] bf16   @ 0            (12,800,000)
//   pairs  : [N_EDGES] int2       @ 12,800,000   ( 4,800,000)  {eid, src}
//   off    : [N_NODES+1] int      @ 17,600,000   (   200,016)
//   cursor : [N_NODES] int        @ 17,800,016   (   200,000)
//   deg    : [N_NODES] int        @ 18,000,016   (   200,000)
//   bsum   : [256] int            @ 18,200,016   (     1,024)
//   W1T    : [1024*128] bf16      @ 18,201,040   (   262,144)   [n][k]
//   W2T    : [128*1024] bf16      @ 18,463,184   (   262,144)   [n][k]
// ---------------------------------------------------------------------------
#define WS_H      0
#define WS_PAIRS  12800000
#define WS_OFF    17600000
#define WS_CURSOR 17800016
#define WS_DEG    18000016
#define WS_BSUM   18200016
#define WS_W1T    18201040
#define WS_W2T    18463184

typedef short bf16x8 __attribute__((ext_vector_type(8)));
typedef short s16x4  __attribute__((ext_vector_type(4)));
typedef float f32x4  __attribute__((ext_vector_type(4)));
typedef int   i32x2  __attribute__((ext_vector_type(2)));

// ---------------------------------------------------------------------------
// CSR step 1: histogram of dst
// ---------------------------------------------------------------------------
__global__ __launch_bounds__(256) void hist_kernel(
    const int* __restrict__ dst, int* __restrict__ deg)
{
    int e = blockIdx.x * blockDim.x + threadIdx.x;
    if (e < N_EDGES) atomicAdd(&deg[dst[e]], 1);
}

// ---------------------------------------------------------------------------
// CSR step 2a: per-block sums of deg (coalesced). 196 blocks x 256.
// ---------------------------------------------------------------------------
__global__ __launch_bounds__(256) void scan1_kernel(
    const int* __restrict__ deg, int* __restrict__ bsum)
{
    __shared__ int red[256];
    int t = threadIdx.x;
    int idx = blockIdx.x * 256 + t;
    red[t] = (idx < N_NODES) ? deg[idx] : 0;
    __syncthreads();
    for (int s = 128; s > 0; s >>= 1) {
        if (t < s) red[t] += red[t + s];
        __syncthreads();
    }
    if (t == 0) bsum[blockIdx.x] = red[0];
}

// ---------------------------------------------------------------------------
// CSR step 2b: exclusive scan of 196 block sums (single small block).
// Also writes off[N_NODES] = total.
// ---------------------------------------------------------------------------
#define SCAN_NB 196
__global__ __launch_bounds__(256) void scan2_kernel(
    int* __restrict__ bsum, int* __restrict__ off)
{
    __shared__ int sh[256];
    int t = threadIdx.x;
    int v = (t < SCAN_NB) ? bsum[t] : 0;
    sh[t] = v;
    __syncthreads();
    for (int ofs = 1; ofs < 256; ofs <<= 1) {
        int u = (t >= ofs) ? sh[t - ofs] : 0;
        __syncthreads();
        sh[t] += u;
        __syncthreads();
    }
    if (t < SCAN_NB) bsum[t] = sh[t] - v;       // exclusive
    if (t == 255) off[N_NODES] = sh[255];       // total == N_EDGES
}

// ---------------------------------------------------------------------------
// CSR step 2c: block-local scan + block offset -> off[], cursor[]
// ---------------------------------------------------------------------------
__global__ __launch_bounds__(256) void scan3_kernel(
    const int* __restrict__ deg, const int* __restrict__ bsum,
    int* __restrict__ off, int* __restrict__ cursor)
{
    __shared__ int sh[256];
    int t = threadIdx.x;
    int idx = blockIdx.x * 256 + t;
    int v = (idx < N_NODES) ? deg[idx] : 0;
    sh[t] = v;
    __syncthreads();
    for (int ofs = 1; ofs < 256; ofs <<= 1) {
        int u = (t >= ofs) ? sh[t - ofs] : 0;
        __syncthreads();
        sh[t] += u;
        __syncthreads();
    }
    if (idx < N_NODES) {
        int ex = bsum[blockIdx.x] + sh[t] - v;
        off[idx] = ex;
        cursor[idx] = ex;
    }
}

// ---------------------------------------------------------------------------
// CSR step 3: drop {eid, src} pairs into dst buckets.
// ---------------------------------------------------------------------------
__global__ __launch_bounds__(256) void fill_kernel(
    const int* __restrict__ dst, const int* __restrict__ src,
    int* __restrict__ cursor, int* __restrict__ pairs)
{
    int e = blockIdx.x * blockDim.x + threadIdx.x;
    if (e < N_EDGES) {
        int s = src[e];                       // coalesced
        int pos = atomicAdd(&cursor[dst[e]], 1);
        i32x2 v; v.x = e; v.y = s;
        *(i32x2*)(pairs + 2 * (size_t)pos) = v;   // 8B scatter
    }
}

// ---------------------------------------------------------------------------
// Merged transpose + fp32->bf16 convert for BOTH weight matrices in one
// launch. Blocks [0,128): W1[128][1024] -> W1T[1024][128].
// Blocks [128,256): W2[1024][128] -> W2T[128][1024].
// ---------------------------------------------------------------------------
__global__ __launch_bounds__(256) void transpose_cvt2_kernel(
    const float* __restrict__ W1, __hip_bfloat16* __restrict__ w1t,
    const float* __restrict__ W2, __hip_bfloat16* __restrict__ w2t)
{
    __shared__ float tile[32][33];
    int b = blockIdx.x;
    const float* in;
    __hip_bfloat16* outp;
    int rows, cols, c0, r0;
    if (b < 128) {
        in = W1; outp = w1t; rows = D_IN; cols = D_HID;
        c0 = (b & 31) * 32; r0 = (b >> 5) * 32;          // grid (32,4)
    } else {
        int bb = b - 128;
        in = W2; outp = w2t; rows = D_HID; cols = D_OUT;
        c0 = (bb & 3) * 32; r0 = (bb >> 2) * 32;         // grid (4,32)
    }
    int tx = threadIdx.x & 31, ty = threadIdx.x >> 5;    // ty 0..7
    #pragma unroll
    for (int i = 0; i < 32; i += 8)
        tile[ty + i][tx] = in[(size_t)(r0 + ty + i) * cols + (c0 + tx)];
    __syncthreads();
    #pragma unroll
    for (int i = 0; i < 32; i += 8)
        outp[(size_t)(c0 + ty + i) * rows + (r0 + tx)] =
            __float2bfloat16(tile[tx][ty + i]);
}

// ---------------------------------------------------------------------------
// STANDALONE gather: one wave per node, full occupancy, BW-bound.
// Wave-uniform {eid,src} pair loads, full-wave float2/lane row loads (512B
// coalesced per edge), 8-edge unroll into 4 independent accumulators.
// ---------------------------------------------------------------------------
__global__ __launch_bounds__(256) void gather_kernel(
    const float* __restrict__ feat,
    const float* __restrict__ edge_feat,
    const int*   __restrict__ pairs,          // [E] {eid, src}
    const int*   __restrict__ off,
    __hip_bfloat16* __restrict__ hbf)
{
    const int wv   = threadIdx.x >> 6;
    const int lane = threadIdx.x & 63;
    const int n = blockIdx.x * 4 + wv;
    if (n >= N_NODES) return;

    int i   = __builtin_amdgcn_readfirstlane(off[n]);
    int end = __builtin_amdgcn_readfirstlane(off[n + 1]);

    float2 a0 = make_float2(0.f, 0.f), a1 = a0, a2 = a0, a3 = a0;

    for (; i + 8 <= end; i += 8) {
        i32x2 p0 = *(const i32x2*)(pairs + 2 * (size_t)(i + 0));
        i32x2 p1 = *(const i32x2*)(pairs + 2 * (size_t)(i + 1));
        i32x2 p2 = *(const i32x2*)(pairs + 2 * (size_t)(i + 2));
        i32x2 p3 = *(const i32x2*)(pairs + 2 * (size_t)(i + 3));
        i32x2 p4 = *(const i32x2*)(pairs + 2 * (size_t)(i + 4));
        i32x2 p5 = *(const i32x2*)(pairs + 2 * (size_t)(i + 5));
        i32x2 p6 = *(const i32x2*)(pairs + 2 * (size_t)(i + 6));
        i32x2 p7 = *(const i32x2*)(pairs + 2 * (size_t)(i + 7));
        float2 e0 = ((const float2*)(edge_feat + (size_t)p0.x * D_IN))[lane];
        float2 g0 = ((const float2*)(feat      + (size_t)p0.y * D_IN))[lane];
        float2 e1 = ((const float2*)(edge_feat + (size_t)p1.x * D_IN))[lane];
        float2 g1 = ((const float2*)(feat      + (size_t)p1.y * D_IN))[lane];
        float2 e2 = ((const float2*)(edge_feat + (size_t)p2.x * D_IN))[lane];
        float2 g2 = ((const float2*)(feat      + (size_t)p2.y * D_IN))[lane];
        float2 e3 = ((const float2*)(edge_feat + (size_t)p3.x * D_IN))[lane];
        float2 g3 = ((const float2*)(feat      + (size_t)p3.y * D_IN))[lane];
        float2 e4 = ((const float2*)(edge_feat + (size_t)p4.x * D_IN))[lane];
        float2 g4 = ((const float2*)(feat      + (size_t)p4.y * D_IN))[lane];
        float2 e5 = ((const float2*)(edge_feat + (size_t)p5.x * D_IN))[lane];
        float2 g5 = ((const float2*)(feat      + (size_t)p5.y * D_IN))[lane];
        float2 e6 = ((const float2*)(edge_feat + (size_t)p6.x * D_IN))[lane];
        float2 g6 = ((const float2*)(feat      + (size_t)p6.y * D_IN))[lane];
        float2 e7 = ((const float2*)(edge_feat + (size_t)p7.x * D_IN))[lane];
        float2 g7 = ((const float2*)(feat      + (size_t)p7.y * D_IN))[lane];
        a0.x += e0.x + g0.x;  a0.y += e0.y + g0.y;
        a1.x += e1.x + g1.x;  a1.y += e1.y + g1.y;
        a2.x += e2.x + g2.x;  a2.y += e2.y + g2.y;
        a3.x += e3.x + g3.x;  a3.y += e3.y + g3.y;
        a0.x += e4.x + g4.x;  a0.y += e4.y + g4.y;
        a1.x += e5.x + g5.x;  a1.y += e5.y + g5.y;
        a2.x += e6.x + g6.x;  a2.y += e6.y + g6.y;
        a3.x += e7.x + g7.x;  a3.y += e7.y + g7.y;
    }
    for (; i + 2 <= end; i += 2) {
        i32x2 p0 = *(const i32x2*)(pairs + 2 * (size_t)(i + 0));
        i32x2 p1 = *(const i32x2*)(pairs + 2 * (size_t)(i + 1));
        float2 e0 = ((const float2*)(edge_feat + (size_t)p0.x * D_IN))[lane];
        float2 g0 = ((const float2*)(feat      + (size_t)p0.y * D_IN))[lane];
        float2 e1 = ((const float2*)(edge_feat + (size_t)p1.x * D_IN))[lane];
        float2 g1 = ((const float2*)(feat      + (size_t)p1.y * D_IN))[lane];
        a0.x += e0.x + g0.x;  a0.y += e0.y + g0.y;
        a1.x += e1.x + g1.x;  a1.y += e1.y + g1.y;
    }
    if (i < end) {
        i32x2 p = *(const i32x2*)(pairs + 2 * (size_t)i);
        float2 e = ((const float2*)(edge_feat + (size_t)p.x * D_IN))[lane];
        float2 g = ((const float2*)(feat      + (size_t)p.y * D_IN))[lane];
        a0.x += e.x + g.x;  a0.y += e.y + g.y;
    }
    float sx = (a0.x + a1.x) + (a2.x + a3.x);
    float sy = (a0.y + a1.y) + (a2.y + a3.y);
    __hip_bfloat162 hv;
    hv.x = __float2bfloat16(sx);
    hv.y = __float2bfloat16(sy);
    ((__hip_bfloat162*)(hbf + (size_t)n * D_IN))[lane] = hv;
}

// ---------------------------------------------------------------------------
// MFMA MLP, operand-swapped layer 1. 64 nodes/block, 4 waves, chunk = 128
// hidden cols (8 chunks, 8 barriers/block instead of 16).
//
// Layer1 (SWAPPED): D = W1T-frag (A) x h-frag (B). The fragment bytes are
//   identical to the previous version (bfrag pattern used as A, afrag
//   pattern used as B); the output flips to D[hid][node]: lane holds
//   H1[node = nt*16+lane&15][hid = hid0 + (lane>>4)*4 + r], r=0..3.
//   -> per-lane: node FIXED, 4 CONSECUTIVE hidden  =>  relu+cvt packs to
//   one ds_write_b64 per nt (4 b64 writes/wave/64-hid vs 16 scalar b16),
//   and bias is a single float4 vector load per 16-hid tile.
//   h-frags come straight from L2-resident hbf (no h_s staging, no extra
//   barrier); wave wv owns hidden rows [jb + wv*32, +32).
//
// Layer2: unchanged math: A = q_s fragment (node=lane&15), B = W2T rows.
//   Split into two K=64 halves to keep a2f at 32 VGPRs.
//   q_s double-buffered -> ONE __syncthreads() per 128-col chunk.
// ---------------------------------------------------------------------------
#define QS_STRIDE 136   // shorts per q_s row (272 B = 17*16, banks shift 4/row)

__global__ __launch_bounds__(256) void mlp_mfma_kernel(
    const __hip_bfloat16* __restrict__ hbf,   // [N][128]
    const __hip_bfloat16* __restrict__ w1t,   // [1024][128]
    const float* __restrict__ b1,             // [1024]
    const __hip_bfloat16* __restrict__ w2t,   // [128][1024]
    const float* __restrict__ b2,             // [128]
    float* __restrict__ out)                  // [N][128]
{
    __shared__ __align__(16) short q_s[2][64 * QS_STRIDE];   // 34.8 KB

    const int t    = threadIdx.x;
    const int wv   = t >> 6;
    const int lane = t & 63;
    const int half = lane >> 4;    // quad 0..3
    const int lid  = lane & 15;
    const int nb   = blockIdx.x * 64;

    const short* hs  = (const short*)hbf;
    const short* w1s = (const short*)w1t;
    const short* w2s = (const short*)w2t;

    // ---- h fragments (B-operand for swapped layer1), straight from L2.
    //      lane holds h[node = nt*16+lid][k = ks*32 + half*8 + j]
    bf16x8 hfrag[4][4];
    #pragma unroll
    for (int nt = 0; nt < 4; ++nt) {
        int row = nb + nt * 16 + lid;
        if (row >= N_NODES) row = N_NODES - 1;   // clamp: dup valid row, no NaN
        #pragma unroll
        for (int ks = 0; ks < 4; ++ks)
            hfrag[nt][ks] = *(const bf16x8*)&hs[(size_t)row * 128 + ks * 32 + half * 8];
    }

    f32x4 acc[4][2];
    #pragma unroll
    for (int mt = 0; mt < 4; ++mt) {
        acc[mt][0] = f32x4{0.f, 0.f, 0.f, 0.f};
        acc[mt][1] = f32x4{0.f, 0.f, 0.f, 0.f};
    }

    int pb = 0;
    for (int jb = 0; jb < D_HID; jb += 128, pb ^= 1) {
        // ---- layer 1 (swapped): wave wv computes hidden [jb+wv*32, +32) ----
        #pragma unroll
        for (int ht = 0; ht < 2; ++ht) {
            const int hid0 = jb + wv * 32 + ht * 16;
            bf16x8 w1f[4];
            #pragma unroll
            for (int ks = 0; ks < 4; ++ks)
                w1f[ks] = *(const bf16x8*)&w1s[(size_t)(hid0 + lid) * 128 + ks * 32 + half * 8];
            f32x4 bias4 = *(const f32x4*)&b1[hid0 + half * 4];
            #pragma unroll
            for (int nt = 0; nt < 4; ++nt) {
                f32x4 c = bias4;
                #pragma unroll
                for (int ks = 0; ks < 4; ++ks)
                    c = __builtin_amdgcn_mfma_f32_16x16x32_bf16(w1f[ks], hfrag[nt][ks], c, 0, 0, 0);
                // c[r] = H1[node=nt*16+lid][hid0 + half*4 + r]
                s16x4 hv;
                #pragma unroll
                for (int r = 0; r < 4; ++r) {
                    float v = fmaxf(c[r], 0.f);
                    __hip_bfloat16 bv = __float2bfloat16(v);
                    hv[r] = *(short*)&bv;
                }
                *(s16x4*)&q_s[pb][(nt * 16 + lid) * QS_STRIDE + wv * 32 + ht * 16 + half * 4] = hv;
            }
        }
        __syncthreads();   // q_s[pb] complete; also orders next write to pb^1
                           // after the previous chunk's reads of pb^1.

        // ---- layer 2: two K=64 halves of this chunk ----
        #pragma unroll
        for (int kh = 0; kh < 2; ++kh) {
            bf16x8 a2f[4][2];
            #pragma unroll
            for (int mt = 0; mt < 4; ++mt)
                #pragma unroll
                for (int ks = 0; ks < 2; ++ks)
                    a2f[mt][ks] = *(const bf16x8*)&q_s[pb][(mt * 16 + lid) * QS_STRIDE + kh * 64 + ks * 32 + half * 8];
            #pragma unroll
            for (int nt = 0; nt < 2; ++nt) {
                #pragma unroll
                for (int ks = 0; ks < 2; ++ks) {
                    bf16x8 b2f = *(const bf16x8*)&w2s[(size_t)(wv * 32 + nt * 16 + lid) * 1024 + jb + kh * 64 + ks * 32 + half * 8];
                    #pragma unroll
                    for (int mt = 0; mt < 4; ++mt)
                        acc[mt][nt] = __builtin_amdgcn_mfma_f32_16x16x32_bf16(a2f[mt][ks], b2f, acc[mt][nt], 0, 0, 0);
                }
            }
        }
    }

    // ---- epilogue ----
    #pragma unroll
    for (int nt = 0; nt < 2; ++nt) {
        int col = wv * 32 + nt * 16 + lid;
        float bv = b2[col];
        #pragma unroll
        for (int mt = 0; mt < 4; ++mt) {
            #pragma unroll
            for (int r = 0; r < 4; ++r) {
                int row = nb + mt * 16 + half * 4 + r;
                if (row < N_NODES)
                    out[(size_t)row * D_OUT + col] = acc[mt][nt][r] + bv;
            }
        }
    }
}

// ---------------------------------------------------------------------------
extern "C" void kernel_launch(void* const* d_in, const int* in_sizes, int n_in,
                              void* d_out, int out_size, void* d_ws, size_t ws_size,
                              hipStream_t stream) {
    const float* feat      = (const float*)d_in[0];
    const float* edge_feat = (const float*)d_in[1];
    const int*   src       = (const int*)d_in[2];
    const int*   dst       = (const int*)d_in[3];
    const float* W1        = (const float*)d_in[4];
    const float* b1        = (const float*)d_in[5];
    const float* W2        = (const float*)d_in[6];
    const float* b2        = (const float*)d_in[7];
    float* out = (float*)d_out;

    char* ws = (char*)d_ws;
    __hip_bfloat16* hbf = (__hip_bfloat16*)(ws + WS_H);
    int*   pairs  = (int*)(ws + WS_PAIRS);
    int*   off    = (int*)(ws + WS_OFF);
    int*   cursor = (int*)(ws + WS_CURSOR);
    int*   deg    = (int*)(ws + WS_DEG);
    int*   bsum   = (int*)(ws + WS_BSUM);
    __hip_bfloat16* w1t = (__hip_bfloat16*)(ws + WS_W1T);
    __hip_bfloat16* w2t = (__hip_bfloat16*)(ws + WS_W2T);

    hipMemsetAsync(deg, 0, (size_t)N_NODES * sizeof(int), stream);

    // CSR build
    hist_kernel<<<(N_EDGES + 255) / 256, 256, 0, stream>>>(dst, deg);
    scan1_kernel<<<SCAN_NB, 256, 0, stream>>>(deg, bsum);
    scan2_kernel<<<1, 256, 0, stream>>>(bsum, off);
    scan3_kernel<<<SCAN_NB, 256, 0, stream>>>(deg, bsum, off, cursor);
    fill_kernel<<<(N_EDGES + 255) / 256, 256, 0, stream>>>(dst, src, cursor, pairs);

    // both weight transposes in one launch
    transpose_cvt2_kernel<<<256, 256, 0, stream>>>(W1, w1t, W2, w2t);

    // standalone gather at full occupancy (one wave per node)
    gather_kernel<<<(N_NODES + 3) / 4, 256, 0, stream>>>(
        feat, edge_feat, pairs, off, hbf);

    // MFMA MLP (operand-swapped layer 1)
    mlp_mfma_kernel<<<(N_NODES + 63) / 64, 256, 0, stream>>>(
        hbf, w1t, b1, w2t, b2, out);
}